// Round 7
// baseline (182.325 us; speedup 1.0000x reference)
//
#include <hip/hip_runtime.h>
#include <math.h>

#define N_NODES 100000
#define N_EDGES 3200000
#define EPS_F 1e-6f
#define PAIRS   (N_EDGES / 2)           // 1,600,000

// ---- prep geometry: 256 blocks x 1024 thr, 160 KB bf16 v-table in LDS ----
#define TBL_N   80000                   // bf16 nodes in LDS (160,000 B); rest spill to L2
#define GNB     256
#define GSTRIDE (GNB * 1024)            // 262,144 threads
#define NVARW   (GNB * 16)              // per-wave varsum partials (4096)

// ---- scatter: PROVEN geometry (grid 256, 7 iters/block) + register prefetch ----
// R0..R6 data: throughput tracks iterations/block (7 good, 2-3 bad), NOT
// occupancy (R6: 2 blk/CU, occ 63% -> WORSE). => latency-bound issue->wait->
// consume loop. Fix: double-buffer the 8-load batch in registers.
#define SLICE_N 12500                   // 8*12500 = 100000
#define NSLICE  8
#define NCHUNK  32
#define C_PAIRS (PAIRS / NCHUNK)        // 50000 pairs per chunk (800 KB, ~7 iters)
#define SBATCH  8

#define NKCLB   391                     // ceil(100000/256)
#define NPACKB  196                     // 50176 threads >= 50000

// ws layout (4-byte words) — ~26.3 MB
//   CNT_WORD : done-counter (reset by pack_kernel)
//   PK_OFF   : u64 pack[N_EDGES]  lo = src | dst<<17 ; hi = (dst>>15) | cur<<2
//   NS_OFF   : fp32 node_sum[N_NODES] (zeroed by pack; scatter atomically adds)
//   VARP_OFF : per-WAVE float4 {s0,s1,q0,q1}[NVARW]
//   KCLP_OFF : per-block kcl partial [NKCLB]
//   VBF_OFF  : bf16 v[N_NODES] (packed by pack_kernel; table source + spill reads)
#define CNT_WORD  32
#define PK_OFF    64
#define NS_OFF    (PK_OFF + 2 * N_EDGES)          // 6,400,064
#define VARP_OFF  (NS_OFF + N_NODES)              // 6,500,064
#define KCLP_OFF  (VARP_OFF + 4 * NVARW)          // 6,516,448
#define VBF_OFF   (KCLP_OFF + 512)                // 6,516,960
#define WS_FLOATS (VBF_OFF + N_NODES / 2 + 64)

__device__ __forceinline__ float wave_reduce(float v) {
    #pragma unroll
    for (int off = 32; off > 0; off >>= 1) v += __shfl_down(v, off, 64);
    return v;
}

__device__ __forceinline__ void fadd_agent(float* p, float v) {
    unsafeAtomicAdd(p, v);   // hw fp32 atomic, device scope
}

// bf16 pack/unpack (RNE)
__device__ __forceinline__ unsigned short f2bf(float f) {
    unsigned u = __float_as_uint(f);
    unsigned r = ((u >> 16) & 1u) + 0x7FFFu;
    return (unsigned short)((u + r) >> 16);
}
__device__ __forceinline__ float bf2f(unsigned short h) {
    return __uint_as_float(((unsigned)h) << 16);
}

// ---------------- pass 0: pack v to bf16 + zero node_sum + reset done-counter ----------------
__global__ __launch_bounds__(256) void pack_kernel(
    const float* __restrict__ nf, float* __restrict__ ws)
{
    const int t = blockIdx.x * 256 + threadIdx.x;
    if (t == 0) ((unsigned*)ws)[CNT_WORD] = 0;
    if (t < N_NODES / 2) {
        const float4 a = ((const float4*)nf)[2 * t];       // node 2t   (v = .x)
        const float4 b = ((const float4*)nf)[2 * t + 1];   // node 2t+1 (v = .x)
        ((unsigned*)(ws + VBF_OFF))[t] = (unsigned)f2bf(a.x) | ((unsigned)f2bf(b.x) << 16);
    }
    for (int j = t; j < N_NODES; j += NPACKB * 256) ws[NS_OFF + j] = 0.f;
}

// ---------------- pass 1: prep = LDS v-table gather + pack ids+cur + varsum ----------------
// 80000 bf16 nodes in 160,000 B LDS (80% hit); spill ids read the bf16 global
// table (L2-resident). Per-wave varsum partials -> global.
__global__ __launch_bounds__(1024, 4) void prep_kernel(
    const void*   __restrict__ eidx,
    const float*  __restrict__ logits,
    const float2* __restrict__ params,
    float*        __restrict__ ws)
{
    __shared__ unsigned vlds[TBL_N / 2];   // 160,000 B

    // fill table (coalesced uint loads of packed bf16)
    const unsigned* vsrc = (const unsigned*)(ws + VBF_OFF);
    for (int j = threadIdx.x; j < TBL_N / 2; j += 1024) vlds[j] = vsrc[j];

    const int* i32 = (const int*)eidx;
    // int64 values < 2^31 have zero hi-words at every odd int32 slot;
    // int32 has random node ids there (16 zeros ~ impossible).
    int any = 0;
    #pragma unroll
    for (int k = 1; k < 32; k += 2) any |= i32[k];
    const bool is32 = (any != 0);

    __syncthreads();
    const unsigned short* vl = (const unsigned short*)vlds;
    const unsigned short* vg = (const unsigned short*)(ws + VBF_OFF);

    const int gtid = blockIdx.x * 1024 + threadIdx.x;
    int4* pk = (int4*)(ws + PK_OFF);

    float s0 = 0.f, s1 = 0.f, q0 = 0.f, q1 = 0.f;

    #define VGET(id) bf2f(((unsigned)(id) < TBL_N) ? vl[id] : vg[id])

    for (int p = gtid; p < PAIRS; p += 2 * GSTRIDE) {
        const int pb  = p + GSTRIDE;
        const int pbc = (pb < PAIRS) ? pb : p;   // clamp: loads stay unconditional

        int2 spA, dpA, spB, dpB;
        if (is32) {
            spA = ((const int2*)i32)[p];
            spB = ((const int2*)i32)[pbc];
            dpA = ((const int2*)(i32 + N_EDGES))[p];
            dpB = ((const int2*)(i32 + N_EDGES))[pbc];
        } else {
            const int4 a0 = ((const int4*)i32)[p];
            const int4 a1 = ((const int4*)i32)[pbc];
            const int4 b0 = ((const int4*)(i32 + 2 * N_EDGES))[p];
            const int4 b1 = ((const int4*)(i32 + 2 * N_EDGES))[pbc];
            spA = make_int2(a0.x, a0.z);  spB = make_int2(a1.x, a1.z);
            dpA = make_int2(b0.x, b0.z);  dpB = make_int2(b1.x, b1.z);
        }
        const float4 ppA = ((const float4*)params)[p];
        const float4 ppB = ((const float4*)params)[pbc];
        const float2 lgA = ((const float2*)logits)[p];
        const float2 lgB = ((const float2*)logits)[pbc];

        // 8 lookups: ~80% LDS (cheap), ~20% L2 bf16 spill
        const float vsA0 = VGET(spA.x), vdA0 = VGET(dpA.x);
        const float vsA1 = VGET(spA.y), vdA1 = VGET(dpA.y);
        const float vsB0 = VGET(spB.x), vdB0 = VGET(dpB.x);
        const float vsB1 = VGET(spB.y), vdB1 = VGET(dpB.y);

        const float wA0 = (1.0f / (1.0f + __expf(-lgA.x))) / (ppA.x + ppA.y + EPS_F);
        const float wA1 = (1.0f / (1.0f + __expf(-lgA.y))) / (ppA.z + ppA.w + EPS_F);
        const float wB0 = (1.0f / (1.0f + __expf(-lgB.x))) / (ppB.x + ppB.y + EPS_F);
        const float wB1 = (1.0f / (1.0f + __expf(-lgB.y))) / (ppB.z + ppB.w + EPS_F);

        const float cA0 = fabsf(vsA0 - vdA0) * wA0;
        const float cA1 = fabsf(vsA1 - vdA1) * wA1;
        const float cB0 = fabsf(vsB0 - vdB0) * wB0;
        const float cB1 = fabsf(vsB1 - vdB1) * wB1;

        int4 oA, oB;
        oA.x = (int)((unsigned)spA.x | ((unsigned)dpA.x << 17));
        oA.y = (int)((((unsigned)dpA.x) >> 15) | ((unsigned)f2bf(cA0) << 2));
        oA.z = (int)((unsigned)spA.y | ((unsigned)dpA.y << 17));
        oA.w = (int)((((unsigned)dpA.y) >> 15) | ((unsigned)f2bf(cA1) << 2));
        oB.x = (int)((unsigned)spB.x | ((unsigned)dpB.x << 17));
        oB.y = (int)((((unsigned)dpB.x) >> 15) | ((unsigned)f2bf(cB0) << 2));
        oB.z = (int)((unsigned)spB.y | ((unsigned)dpB.y << 17));
        oB.w = (int)((((unsigned)dpB.y) >> 15) | ((unsigned)f2bf(cB1) << 2));

        pk[p] = oA;
        s0 += ppA.x + ppA.z;  s1 += ppA.y + ppA.w;
        q0 += ppA.x * ppA.x + ppA.z * ppA.z;
        q1 += ppA.y * ppA.y + ppA.w * ppA.w;
        if (pb < PAIRS) {
            pk[pb] = oB;
            s0 += ppB.x + ppB.z;  s1 += ppB.y + ppB.w;
            q0 += ppB.x * ppB.x + ppB.z * ppB.z;
            q1 += ppB.y * ppB.y + ppB.w * ppB.w;
        }
    }
    #undef VGET

    s0 = wave_reduce(s0); s1 = wave_reduce(s1);
    q0 = wave_reduce(q0); q1 = wave_reduce(q1);

    if ((threadIdx.x & 63) == 0) {
        float4 o; o.x = s0; o.y = s1; o.z = q0; o.w = q1;
        ((float4*)(ws + VARP_OFF))[blockIdx.x * 16 + (threadIdx.x >> 6)] = o;
    }
}

// ---------------- pass 2: LDS-binned scatter, grid 256, register-prefetch dbuf ----------------
// Issue iteration k+1's 8 int4 loads BEFORE consuming iteration k: the L2-hit
// latency hides under the decode+LDS-atomic consume phase (T14 / G15 pattern).
// Slice partners of chunk c: blockIdx = c + 32*s ≡ c (mod 8) -> same XCD;
// 4 chunks/XCD * 800 KB = 3.2 MB < 4 MB L2.
__global__ __launch_bounds__(1024) void scatter_kernel(float* __restrict__ ws)
{
    __shared__ float bins[SLICE_N];   // 50,000 B

    const int c  = blockIdx.x & (NCHUNK - 1);
    const int s  = blockIdx.x >> 5;
    const unsigned lo = (unsigned)(s * SLICE_N);

    for (int j = threadIdx.x; j < SLICE_N; j += 1024) bins[j] = 0.f;
    __syncthreads();

    const int4* pk = (const int4*)(ws + PK_OFF);

    const int p0   = c * C_PAIRS;
    const int p1   = p0 + C_PAIRS;
    const int STEP = 1024 * SBATCH;

    int4 q[SBATCH], r[SBATCH];
    int base = p0 + (int)threadIdx.x;

    #pragma unroll
    for (int k = 0; k < SBATCH; ++k) {            // prologue: load batch 0
        int p = base + k * 1024;
        p = (p < p1) ? p : (p1 - 1);
        q[k] = pk[p];
    }

    while (base < p1) {
        const int nb = base + STEP;
        if (nb < p1) {                            // prefetch batch k+1
            #pragma unroll
            for (int k = 0; k < SBATCH; ++k) {
                int p = nb + k * 1024;
                p = (p < p1) ? p : (p1 - 1);
                r[k] = pk[p];
            }
        }
        #pragma unroll
        for (int k = 0; k < SBATCH; ++k) {        // consume batch k
            const int p = base + k * 1024;
            if (p < p1) {
                const unsigned lo0 = (unsigned)q[k].x, hi0 = (unsigned)q[k].y;
                const unsigned lo1 = (unsigned)q[k].z, hi1 = (unsigned)q[k].w;
                const unsigned s0 = (lo0 & 0x1FFFFu) - lo;
                const unsigned d0 = ((lo0 >> 17) | ((hi0 & 3u) << 15)) - lo;
                const unsigned s1 = (lo1 & 0x1FFFFu) - lo;
                const unsigned d1 = ((lo1 >> 17) | ((hi1 & 3u) << 15)) - lo;
                const float c0 = bf2f((unsigned short)((hi0 >> 2) & 0xFFFFu));
                const float c1 = bf2f((unsigned short)((hi1 >> 2) & 0xFFFFu));
                if (d0 < SLICE_N) atomicAdd(&bins[d0],  c0);
                if (s0 < SLICE_N) atomicAdd(&bins[s0], -c0);
                if (d1 < SLICE_N) atomicAdd(&bins[d1],  c1);
                if (s1 < SLICE_N) atomicAdd(&bins[s1], -c1);
            }
        }
        base = nb;
        if (base < p1) {
            #pragma unroll
            for (int k = 0; k < SBATCH; ++k) q[k] = r[k];
        }
    }
    __syncthreads();

    // flush: one device-scope fp32 atomic per NON-ZERO bin (~63% at lambda=1)
    float* ns = ws + NS_OFF + lo;
    for (int j = threadIdx.x; j < SLICE_N; j += 1024) {
        const float v = bins[j];
        if (v != 0.f) fadd_agent(ns + j, v);
    }
}

// ---------------- pass 3: square node_sum + reduce; LAST block folds final ----------------
__global__ __launch_bounds__(256) void kclfinal_kernel(float* __restrict__ ws,
                                                       float* __restrict__ out)
{
    __shared__ float red[4];
    __shared__ unsigned last;

    const int i = blockIdx.x * blockDim.x + threadIdx.x;
    float acc = 0.f;
    if (i < N_NODES) {
        const float v = ws[NS_OFF + i];
        acc = v * v;
    }
    acc = wave_reduce(acc);
    if ((threadIdx.x & 63) == 0) red[threadIdx.x >> 6] = acc;
    __syncthreads();
    if (threadIdx.x == 0) {
        ws[KCLP_OFF + blockIdx.x] = red[0] + red[1] + red[2] + red[3];
        __threadfence();   // KCLP store visible before counter bump
        const unsigned old = atomicAdd((unsigned*)ws + CNT_WORD, 1u);
        last = (old == NKCLB - 1) ? 1u : 0u;
    }
    __syncthreads();
    if (!last) return;

    // ---- final reduction (one block, 256 threads) ----
    __shared__ float red2[4][5];
    float s0 = 0.f, s1 = 0.f, q0 = 0.f, q1 = 0.f, k = 0.f;

    const float4* vp = (const float4*)(ws + VARP_OFF);   // prep output: kernel-boundary safe
    for (int j = threadIdx.x; j < NVARW; j += 256) {
        const float4 v = vp[j];
        s0 += v.x; s1 += v.y; q0 += v.z; q1 += v.w;
    }
    // KCLP written by other blocks this kernel: cross-XCD L2 not coherent ->
    // read via device-scope atomic RMW (+0.0 returns old value).
    for (int j = threadIdx.x; j < NKCLB; j += 256)
        k += unsafeAtomicAdd(ws + KCLP_OFF + j, 0.0f);

    s0 = wave_reduce(s0); s1 = wave_reduce(s1);
    q0 = wave_reduce(q0); q1 = wave_reduce(q1);
    k  = wave_reduce(k);

    const int wid = threadIdx.x >> 6;
    if ((threadIdx.x & 63) == 0) {
        red2[wid][0] = s0; red2[wid][1] = s1; red2[wid][2] = q0;
        red2[wid][3] = q1; red2[wid][4] = k;
    }
    __syncthreads();
    if (threadIdx.x == 0) {
        float a0 = 0.f, a1 = 0.f, a2 = 0.f, a3 = 0.f, a4 = 0.f;
        #pragma unroll
        for (int w = 0; w < 4; ++w) {
            a0 += red2[w][0]; a1 += red2[w][1]; a2 += red2[w][2];
            a3 += red2[w][3]; a4 += red2[w][4];
        }
        const float n    = (float)N_EDGES;
        const float var0 = (a2 - a0 * a0 / n) / (n - 1.0f);
        const float var1 = (a3 - a1 * a1 / n) / (n - 1.0f);
        out[0] = a4 / (float)N_NODES + 0.5f * (var0 + var1);
    }
}

// ---------------- fallback (ws too small): agent-atomic scatter ----------------
#define FB_NODE_OFF 64
__global__ __launch_bounds__(256) void edge_kernel_fb(
    const float*  __restrict__ nf,
    const void*   __restrict__ eidx,
    const float*  __restrict__ logits,
    const float2* __restrict__ params,
    float*        __restrict__ ws)
{
    const int*       i32 = (const int*)eidx;
    const long long* i64 = (const long long*)eidx;
    int any = 0;
    #pragma unroll
    for (int k = 1; k < 32; k += 2) any |= i32[k];
    const bool is32 = (any != 0);

    float* node_sum = ws + FB_NODE_OFF;
    float* acc      = ws + 1;

    float s0 = 0.f, s1 = 0.f, q0 = 0.f, q1 = 0.f;
    const int tid    = blockIdx.x * blockDim.x + threadIdx.x;
    const int stride = gridDim.x * blockDim.x;
    for (int i = tid; i < N_EDGES; i += stride) {
        int src, dst;
        if (is32) { src = i32[i]; dst = i32[N_EDGES + i]; }
        else      { src = (int)i64[i]; dst = (int)i64[N_EDGES + i]; }
        const float2 ep = params[i];
        const float  p  = 1.0f / (1.0f + __expf(-logits[i]));
        const float cur = fabsf(nf[src * 4] - nf[dst * 4]) / (ep.x + ep.y + EPS_F) * p;
        fadd_agent(node_sum + dst,  cur);
        fadd_agent(node_sum + src, -cur);
        s0 += ep.x; s1 += ep.y; q0 += ep.x * ep.x; q1 += ep.y * ep.y;
    }
    s0 = wave_reduce(s0); s1 = wave_reduce(s1);
    q0 = wave_reduce(q0); q1 = wave_reduce(q1);
    if ((threadIdx.x & 63) == 0) {
        fadd_agent(acc + 0, s0); fadd_agent(acc + 1, s1);
        fadd_agent(acc + 2, q0); fadd_agent(acc + 3, q1);
    }
}

__global__ __launch_bounds__(256) void kcl_kernel_fb(float* __restrict__ ws)
{
    const float* node_sum = ws + FB_NODE_OFF;
    float acc = 0.f;
    const int tid    = blockIdx.x * blockDim.x + threadIdx.x;
    const int stride = gridDim.x * blockDim.x;
    for (int i = tid; i < N_NODES; i += stride) {
        const float v = node_sum[i];
        acc += v * v;
    }
    acc = wave_reduce(acc);
    if ((threadIdx.x & 63) == 0) fadd_agent(ws + 5, acc);
}

__global__ void final_kernel_fb(const float* __restrict__ ws, float* __restrict__ out)
{
    const float s0 = ws[1], s1 = ws[2], q0 = ws[3], q1 = ws[4], k = ws[5];
    const float n  = (float)N_EDGES;
    const float var0 = (q0 - s0 * s0 / n) / (n - 1.0f);
    const float var1 = (q1 - s1 * s1 / n) / (n - 1.0f);
    out[0] = k / (float)N_NODES + 0.5f * (var0 + var1);
}

extern "C" void kernel_launch(void* const* d_in, const int* in_sizes, int n_in,
                              void* d_out, int out_size, void* d_ws, size_t ws_size,
                              hipStream_t stream) {
    const float*  nf     = (const float*)d_in[0];
    const void*   eidx   = d_in[1];
    const float*  logits = (const float*)d_in[2];
    const float2* params = (const float2*)d_in[3];
    float* ws  = (float*)d_ws;
    float* out = (float*)d_out;

    const size_t need = (size_t)WS_FLOATS * sizeof(float);   // ~26.3 MB

    if (ws_size >= need) {
        pack_kernel<<<NPACKB, 256, 0, stream>>>(nf, ws);
        prep_kernel<<<GNB, 1024, 0, stream>>>(eidx, logits, params, ws);
        scatter_kernel<<<NCHUNK * NSLICE, 1024, 0, stream>>>(ws);
        kclfinal_kernel<<<NKCLB, 256, 0, stream>>>(ws, out);
    } else {
        hipMemsetAsync(d_ws, 0, 256 + (size_t)N_NODES * sizeof(float), stream);
        edge_kernel_fb<<<2048, 256, 0, stream>>>(nf, eidx, logits, params, ws);
        kcl_kernel_fb<<<200, 256, 0, stream>>>(ws);
        final_kernel_fb<<<1, 1, 0, stream>>>(ws, out);
    }
}

// Round 8
// 168.595 us; speedup vs baseline: 1.0814x; 1.0814x over previous
//
#include <hip/hip_runtime.h>
#include <math.h>

#define N_NODES 100000
#define N_EDGES 3200000
#define EPS_F 1e-6f
#define PAIRS   (N_EDGES / 2)           // 1,600,000

// ---- prep geometry: 256 blocks x 1024 thr, 160 KB bf16 v-table in LDS ----
#define TBL_N   80000                   // bf16 nodes in LDS (160,000 B); rest spill to L2
#define GNB     256
#define GSTRIDE (GNB * 1024)            // 262,144 threads
#define NVARW   (GNB * 16)              // per-wave varsum partials (4096)

// ---- scatter: R5-proven geometry (grid 256, ~6 iters/block, PART store flush) ----
// Locked by R0-R7 data: grid=256 (no dispatch-wave quantization), deep batch
// loop, PLAIN float4 flush to PART (device-atomic flush to node_sum cost ~10us
// in R6/R7: cross-XCD contended atomics). Prefetch: measured no-op (R7).
#define SLICE_N 12500                   // 8*12500 = 100000
#define NSLICE  8
#define NCHUNK  32
#define C_PAIRS (PAIRS / NCHUNK)        // 50000 pairs per chunk (800 KB)
#define SBATCH  8

#define NKCLB   391                     // ceil(100000/256)
#define NPACKB  196                     // 50176 threads >= 50000

// ws layout (4-byte words) — ~38.7 MB
//   CNT_WORD : done-counter (reset by pack_kernel)
//   PK_OFF   : u64 pack[N_EDGES]  lo = src | dst<<17 ; hi = (dst>>15) | cur<<2
//   PART_OFF : partials[NCHUNK=32][N_NODES]  (12.8 MB)
//   VARP_OFF : per-WAVE float4 {s0,s1,q0,q1}[NVARW]
//   KCLP_OFF : per-block kcl partial [NKCLB]
//   VBF_OFF  : bf16 v[N_NODES] (packed by pack_kernel; table source + spill reads)
#define CNT_WORD  32
#define PK_OFF    64
#define PART_OFF  (PK_OFF + 2 * N_EDGES)          // 6,400,064
#define VARP_OFF  (PART_OFF + NCHUNK * N_NODES)   // 9,600,064
#define KCLP_OFF  (VARP_OFF + 4 * NVARW)          // 9,616,448
#define VBF_OFF   (KCLP_OFF + 512)                // 9,616,960
#define WS_FLOATS (VBF_OFF + N_NODES / 2 + 64)

__device__ __forceinline__ float wave_reduce(float v) {
    #pragma unroll
    for (int off = 32; off > 0; off >>= 1) v += __shfl_down(v, off, 64);
    return v;
}

__device__ __forceinline__ void fadd_agent(float* p, float v) {
    unsafeAtomicAdd(p, v);   // fallback / final-reduce read path
}

// bf16 pack/unpack (RNE)
__device__ __forceinline__ unsigned short f2bf(float f) {
    unsigned u = __float_as_uint(f);
    unsigned r = ((u >> 16) & 1u) + 0x7FFFu;
    return (unsigned short)((u + r) >> 16);
}
__device__ __forceinline__ float bf2f(unsigned short h) {
    return __uint_as_float(((unsigned)h) << 16);
}

// ---------------- pass 0: pack v to bf16 (once) + reset done-counter ----------------
__global__ __launch_bounds__(256) void pack_kernel(
    const float* __restrict__ nf, float* __restrict__ ws)
{
    const int t = blockIdx.x * 256 + threadIdx.x;
    if (t == 0) ((unsigned*)ws)[CNT_WORD] = 0;
    if (t < N_NODES / 2) {
        const float4 a = ((const float4*)nf)[2 * t];       // node 2t   (v = .x)
        const float4 b = ((const float4*)nf)[2 * t + 1];   // node 2t+1 (v = .x)
        ((unsigned*)(ws + VBF_OFF))[t] = (unsigned)f2bf(a.x) | ((unsigned)f2bf(b.x) << 16);
    }
}

// ---------------- pass 1: prep = LDS v-table gather + pack ids+cur + varsum ----------------
// 80000 bf16 nodes in 160,000 B LDS (80% hit); spill ids read the bf16 global
// table (L2-resident). ILP-4: 4 independent pairs/thread -> 8-12 global +
// 16 LDS lookups in flight (prep is latency-bound: VALUBusy ~10% at ILP-2).
__global__ __launch_bounds__(1024, 4) void prep_kernel(
    const void*   __restrict__ eidx,
    const float*  __restrict__ logits,
    const float2* __restrict__ params,
    float*        __restrict__ ws)
{
    __shared__ unsigned vlds[TBL_N / 2];   // 160,000 B

    // fill table (coalesced uint loads of packed bf16)
    const unsigned* vsrc = (const unsigned*)(ws + VBF_OFF);
    for (int j = threadIdx.x; j < TBL_N / 2; j += 1024) vlds[j] = vsrc[j];

    const int* i32 = (const int*)eidx;
    // int64 values < 2^31 have zero hi-words at every odd int32 slot;
    // int32 has random node ids there (16 zeros ~ impossible).
    int any = 0;
    #pragma unroll
    for (int k = 1; k < 32; k += 2) any |= i32[k];
    const bool is32 = (any != 0);

    __syncthreads();
    const unsigned short* vl = (const unsigned short*)vlds;
    const unsigned short* vg = (const unsigned short*)(ws + VBF_OFF);

    const int gtid = blockIdx.x * 1024 + threadIdx.x;
    int4* pk = (int4*)(ws + PK_OFF);

    float s0 = 0.f, s1 = 0.f, q0 = 0.f, q1 = 0.f;

    #define VGET(id) bf2f(((unsigned)(id) < TBL_N) ? vl[id] : vg[id])

    for (int p = gtid; p < PAIRS; p += 4 * GSTRIDE) {
        int pi[4];
        #pragma unroll
        for (int u = 0; u < 4; ++u) {
            const int pp = p + u * GSTRIDE;
            pi[u] = (pp < PAIRS) ? pp : p;   // clamp: loads stay unconditional
        }

        int2 sp[4], dp[4];
        if (is32) {
            #pragma unroll
            for (int u = 0; u < 4; ++u) {
                sp[u] = ((const int2*)i32)[pi[u]];
                dp[u] = ((const int2*)(i32 + N_EDGES))[pi[u]];
            }
        } else {
            #pragma unroll
            for (int u = 0; u < 4; ++u) {
                const int4 a = ((const int4*)i32)[pi[u]];
                const int4 b = ((const int4*)(i32 + 2 * N_EDGES))[pi[u]];
                sp[u] = make_int2(a.x, a.z);
                dp[u] = make_int2(b.x, b.z);
            }
        }

        float4 ppr[4];
        float2 lgr[4];
        #pragma unroll
        for (int u = 0; u < 4; ++u) {
            ppr[u] = ((const float4*)params)[pi[u]];
            lgr[u] = ((const float2*)logits)[pi[u]];
        }

        float vs0[4], vd0[4], vs1[4], vd1[4];
        #pragma unroll
        for (int u = 0; u < 4; ++u) {
            vs0[u] = VGET(sp[u].x);  vd0[u] = VGET(dp[u].x);
            vs1[u] = VGET(sp[u].y);  vd1[u] = VGET(dp[u].y);
        }

        #pragma unroll
        for (int u = 0; u < 4; ++u) {
            const int pp = p + u * GSTRIDE;
            const float w0 = (1.0f / (1.0f + __expf(-lgr[u].x))) / (ppr[u].x + ppr[u].y + EPS_F);
            const float w1 = (1.0f / (1.0f + __expf(-lgr[u].y))) / (ppr[u].z + ppr[u].w + EPS_F);
            const float c0 = fabsf(vs0[u] - vd0[u]) * w0;
            const float c1 = fabsf(vs1[u] - vd1[u]) * w1;

            int4 o;
            o.x = (int)((unsigned)sp[u].x | ((unsigned)dp[u].x << 17));
            o.y = (int)((((unsigned)dp[u].x) >> 15) | ((unsigned)f2bf(c0) << 2));
            o.z = (int)((unsigned)sp[u].y | ((unsigned)dp[u].y << 17));
            o.w = (int)((((unsigned)dp[u].y) >> 15) | ((unsigned)f2bf(c1) << 2));

            if (pp < PAIRS) {
                pk[pp] = o;
                s0 += ppr[u].x + ppr[u].z;
                s1 += ppr[u].y + ppr[u].w;
                q0 += ppr[u].x * ppr[u].x + ppr[u].z * ppr[u].z;
                q1 += ppr[u].y * ppr[u].y + ppr[u].w * ppr[u].w;
            }
        }
    }
    #undef VGET

    s0 = wave_reduce(s0); s1 = wave_reduce(s1);
    q0 = wave_reduce(q0); q1 = wave_reduce(q1);

    if ((threadIdx.x & 63) == 0) {
        float4 o; o.x = s0; o.y = s1; o.z = q0; o.w = q1;
        ((float4*)(ws + VARP_OFF))[blockIdx.x * 16 + (threadIdx.x >> 6)] = o;
    }
}

// ---------------- pass 2: LDS-binned scatter — R5-proven schedule, PART store ----------------
// grid 256 (1 block/CU), 50K pairs/chunk -> ~6 batched iterations, SBATCH=8 int4.
// Slice partners of chunk c: blockIdx = c + 32*s ≡ c (mod 8) -> same XCD;
// 4 chunks/XCD * 800 KB = 3.2 MB < 4 MB L2.
__global__ __launch_bounds__(1024) void scatter_kernel(float* __restrict__ ws)
{
    __shared__ float bins[SLICE_N];   // 50,000 B

    const int c  = blockIdx.x & (NCHUNK - 1);
    const int s  = blockIdx.x >> 5;
    const unsigned lo = (unsigned)(s * SLICE_N);

    for (int j = threadIdx.x; j < SLICE_N; j += 1024) bins[j] = 0.f;
    __syncthreads();

    const int4* pk = (const int4*)(ws + PK_OFF);

    const int p0 = c * C_PAIRS;
    const int p1 = p0 + C_PAIRS;

    for (int base = p0 + (int)threadIdx.x; base < p1; base += 1024 * SBATCH) {
        int4 q[SBATCH];
        #pragma unroll
        for (int k = 0; k < SBATCH; ++k) {
            int p = base + k * 1024;
            p = (p < p1) ? p : (p1 - 1);   // clamp: loads stay unconditional
            q[k] = pk[p];
        }
        #pragma unroll
        for (int k = 0; k < SBATCH; ++k) {
            const int p = base + k * 1024;
            if (p < p1) {
                const unsigned lo0 = (unsigned)q[k].x, hi0 = (unsigned)q[k].y;
                const unsigned lo1 = (unsigned)q[k].z, hi1 = (unsigned)q[k].w;
                const unsigned s0 = (lo0 & 0x1FFFFu) - lo;
                const unsigned d0 = ((lo0 >> 17) | ((hi0 & 3u) << 15)) - lo;
                const unsigned s1 = (lo1 & 0x1FFFFu) - lo;
                const unsigned d1 = ((lo1 >> 17) | ((hi1 & 3u) << 15)) - lo;
                const float c0 = bf2f((unsigned short)((hi0 >> 2) & 0xFFFFu));
                const float c1 = bf2f((unsigned short)((hi1 >> 2) & 0xFFFFu));
                if (d0 < SLICE_N) atomicAdd(&bins[d0],  c0);
                if (s0 < SLICE_N) atomicAdd(&bins[s0], -c0);
                if (d1 < SLICE_N) atomicAdd(&bins[d1],  c1);
                if (s1 < SLICE_N) atomicAdd(&bins[s1], -c1);
            }
        }
    }
    __syncthreads();

    float4* pt4 = (float4*)(ws + PART_OFF + (size_t)c * N_NODES + lo);
    for (int j = threadIdx.x; j < SLICE_N / 4; j += 1024)
        pt4[j] = ((const float4*)bins)[j];
}

// ---------------- pass 3: merge partials + squares; LAST block folds final ----------------
__global__ __launch_bounds__(256) void kclfinal_kernel(float* __restrict__ ws,
                                                       float* __restrict__ out)
{
    __shared__ float red[4];
    __shared__ unsigned last;

    const int i = blockIdx.x * blockDim.x + threadIdx.x;
    float acc = 0.f;
    if (i < N_NODES) {
        const float* p = ws + PART_OFF + i;
        float s = 0.f;
        #pragma unroll 8
        for (int c = 0; c < NCHUNK; ++c) s += p[(size_t)c * N_NODES];
        acc = s * s;
    }
    acc = wave_reduce(acc);
    if ((threadIdx.x & 63) == 0) red[threadIdx.x >> 6] = acc;
    __syncthreads();
    if (threadIdx.x == 0) {
        ws[KCLP_OFF + blockIdx.x] = red[0] + red[1] + red[2] + red[3];
        __threadfence();   // KCLP store visible before counter bump
        const unsigned old = atomicAdd((unsigned*)ws + CNT_WORD, 1u);
        last = (old == NKCLB - 1) ? 1u : 0u;
    }
    __syncthreads();
    if (!last) return;

    // ---- final reduction (one block, 256 threads) ----
    __shared__ float red2[4][5];
    float s0 = 0.f, s1 = 0.f, q0 = 0.f, q1 = 0.f, k = 0.f;

    const float4* vp = (const float4*)(ws + VARP_OFF);   // prep output: kernel-boundary safe
    for (int j = threadIdx.x; j < NVARW; j += 256) {
        const float4 v = vp[j];
        s0 += v.x; s1 += v.y; q0 += v.z; q1 += v.w;
    }
    // KCLP written by other blocks this kernel: cross-XCD L2 not coherent ->
    // read via device-scope atomic RMW (+0.0 returns old value).
    for (int j = threadIdx.x; j < NKCLB; j += 256)
        k += unsafeAtomicAdd(ws + KCLP_OFF + j, 0.0f);

    s0 = wave_reduce(s0); s1 = wave_reduce(s1);
    q0 = wave_reduce(q0); q1 = wave_reduce(q1);
    k  = wave_reduce(k);

    const int wid = threadIdx.x >> 6;
    if ((threadIdx.x & 63) == 0) {
        red2[wid][0] = s0; red2[wid][1] = s1; red2[wid][2] = q0;
        red2[wid][3] = q1; red2[wid][4] = k;
    }
    __syncthreads();
    if (threadIdx.x == 0) {
        float a0 = 0.f, a1 = 0.f, a2 = 0.f, a3 = 0.f, a4 = 0.f;
        #pragma unroll
        for (int w = 0; w < 4; ++w) {
            a0 += red2[w][0]; a1 += red2[w][1]; a2 += red2[w][2];
            a3 += red2[w][3]; a4 += red2[w][4];
        }
        const float n    = (float)N_EDGES;
        const float var0 = (a2 - a0 * a0 / n) / (n - 1.0f);
        const float var1 = (a3 - a1 * a1 / n) / (n - 1.0f);
        out[0] = a4 / (float)N_NODES + 0.5f * (var0 + var1);
    }
}

// ---------------- fallback (ws too small): agent-atomic scatter ----------------
#define FB_NODE_OFF 64
__global__ __launch_bounds__(256) void edge_kernel_fb(
    const float*  __restrict__ nf,
    const void*   __restrict__ eidx,
    const float*  __restrict__ logits,
    const float2* __restrict__ params,
    float*        __restrict__ ws)
{
    const int*       i32 = (const int*)eidx;
    const long long* i64 = (const long long*)eidx;
    int any = 0;
    #pragma unroll
    for (int k = 1; k < 32; k += 2) any |= i32[k];
    const bool is32 = (any != 0);

    float* node_sum = ws + FB_NODE_OFF;
    float* acc      = ws + 1;

    float s0 = 0.f, s1 = 0.f, q0 = 0.f, q1 = 0.f;
    const int tid    = blockIdx.x * blockDim.x + threadIdx.x;
    const int stride = gridDim.x * blockDim.x;
    for (int i = tid; i < N_EDGES; i += stride) {
        int src, dst;
        if (is32) { src = i32[i]; dst = i32[N_EDGES + i]; }
        else      { src = (int)i64[i]; dst = (int)i64[N_EDGES + i]; }
        const float2 ep = params[i];
        const float  p  = 1.0f / (1.0f + __expf(-logits[i]));
        const float cur = fabsf(nf[src * 4] - nf[dst * 4]) / (ep.x + ep.y + EPS_F) * p;
        fadd_agent(node_sum + dst,  cur);
        fadd_agent(node_sum + src, -cur);
        s0 += ep.x; s1 += ep.y; q0 += ep.x * ep.x; q1 += ep.y * ep.y;
    }
    s0 = wave_reduce(s0); s1 = wave_reduce(s1);
    q0 = wave_reduce(q0); q1 = wave_reduce(q1);
    if ((threadIdx.x & 63) == 0) {
        fadd_agent(acc + 0, s0); fadd_agent(acc + 1, s1);
        fadd_agent(acc + 2, q0); fadd_agent(acc + 3, q1);
    }
}

__global__ __launch_bounds__(256) void kcl_kernel_fb(float* __restrict__ ws)
{
    const float* node_sum = ws + FB_NODE_OFF;
    float acc = 0.f;
    const int tid    = blockIdx.x * blockDim.x + threadIdx.x;
    const int stride = gridDim.x * blockDim.x;
    for (int i = tid; i < N_NODES; i += stride) {
        const float v = node_sum[i];
        acc += v * v;
    }
    acc = wave_reduce(acc);
    if ((threadIdx.x & 63) == 0) fadd_agent(ws + 5, acc);
}

__global__ void final_kernel_fb(const float* __restrict__ ws, float* __restrict__ out)
{
    const float s0 = ws[1], s1 = ws[2], q0 = ws[3], q1 = ws[4], k = ws[5];
    const float n  = (float)N_EDGES;
    const float var0 = (q0 - s0 * s0 / n) / (n - 1.0f);
    const float var1 = (q1 - s1 * s1 / n) / (n - 1.0f);
    out[0] = k / (float)N_NODES + 0.5f * (var0 + var1);
}

extern "C" void kernel_launch(void* const* d_in, const int* in_sizes, int n_in,
                              void* d_out, int out_size, void* d_ws, size_t ws_size,
                              hipStream_t stream) {
    const float*  nf     = (const float*)d_in[0];
    const void*   eidx   = d_in[1];
    const float*  logits = (const float*)d_in[2];
    const float2* params = (const float2*)d_in[3];
    float* ws  = (float*)d_ws;
    float* out = (float*)d_out;

    const size_t need = (size_t)WS_FLOATS * sizeof(float);   // ~38.7 MB

    if (ws_size >= need) {
        pack_kernel<<<NPACKB, 256, 0, stream>>>(nf, ws);
        prep_kernel<<<GNB, 1024, 0, stream>>>(eidx, logits, params, ws);
        scatter_kernel<<<NCHUNK * NSLICE, 1024, 0, stream>>>(ws);
        kclfinal_kernel<<<NKCLB, 256, 0, stream>>>(ws, out);
    } else {
        hipMemsetAsync(d_ws, 0, 256 + (size_t)N_NODES * sizeof(float), stream);
        edge_kernel_fb<<<2048, 256, 0, stream>>>(nf, eidx, logits, params, ws);
        kcl_kernel_fb<<<200, 256, 0, stream>>>(ws);
        final_kernel_fb<<<1, 1, 0, stream>>>(ws, out);
    }
}